// Round 14
// baseline (6771.606 us; speedup 1.0000x reference)
//
#include <hip/hip_runtime.h>

typedef _Float16 half2_t __attribute__((ext_vector_type(2)));
typedef _Float16 f16x8   __attribute__((ext_vector_type(8)));
typedef __bf16   bf16x8  __attribute__((ext_vector_type(8)));
typedef float    f32x4   __attribute__((ext_vector_type(4)));
typedef unsigned short u16x8 __attribute__((ext_vector_type(8)));
typedef unsigned int  uint32;
typedef unsigned long long uint64;

#define LSTM_N 32
#define LSTM_T 2048
#define LSTM_D 256
#define LSTM_H 256
#define NG 1024
#define CH 256                    // time-chunk length
#define NCH (LSTM_T / CH)         // 8 chunks
#define MCH (LSTM_N * CH)         // 8192 rows per chunk GEMM

// ---- workspace layout (bytes) ---- (~34.6 MB)
#define OFF_XG   ((size_t)0)
#define SZ_XG    ((size_t)MCH * NG * 4)             // 33,554,432 xg chunk f32
#define OFF_WIHB (OFF_XG + SZ_XG)
#define SZ_WIHB  ((size_t)NG * LSTM_D * 2)          // w_ih bf16
#define OFF_BIAS (OFF_WIHB + SZ_WIHB)
#define SZ_BIAS  ((size_t)4096)
#define OFF_WPK  (OFF_BIAS + SZ_BIAS)
#define SZ_WPK   ((size_t)8 * 8 * 512 * 16)         // 524,288 w_hh f16 MFMA A-frags
#define OFF_CST  (OFF_WPK + SZ_WPK)
#define SZ_CST   ((size_t)LSTM_N * 256 * 4)         // c state f32
#define OFF_HX   (OFF_CST + SZ_CST)
#define SZ_HX    ((size_t)2 * 2 * 2048 * 8)         // 65,536 board (grp, parity, slot)

__device__ __forceinline__ float sigm(float x) { return 1.f / (1.f + __expf(-x)); }
__device__ __forceinline__ float tanh_fast(float x) { return 2.f / (1.f + __expf(-2.f * x)) - 1.f; }

__device__ __forceinline__ unsigned short f2bf(float f) {
  uint32 u = __builtin_bit_cast(uint32, f);
  uint32 r = (u + 0x7FFFu + ((u >> 16) & 1u)) >> 16;
  return (unsigned short)r;
}

// ---------------- kernels ----------------

__global__ void cvt_bf16_k(const float* __restrict__ src, unsigned short* __restrict__ dst, int n) {
  int i = blockIdx.x * blockDim.x + threadIdx.x;
  if (4 * i + 3 < n) {
    float4 v = ((const float4*)src)[i];
    ushort4 o;
    o.x = f2bf(v.x); o.y = f2bf(v.y); o.z = f2bf(v.z); o.w = f2bf(v.w);
    ((ushort4*)dst)[i] = o;
  }
}

__global__ void bias_sum_k(const float* __restrict__ bih, const float* __restrict__ bhh,
                           float* __restrict__ bias) {
  int g = blockIdx.x * blockDim.x + threadIdx.x;
  if (g < NG) bias[g] = bih[g] + bhh[g];
}

// Pack w_hh f32[1024][256] -> MFMA A-fragments (R4-verified lane mapping).
// Scan WG i owns local rows lr in [0,128): gate q=lr>>5, unit u=32i+(lr&31).
// Thread t=(w,l), tile (w,kc): A[row lr=16w+(l&15)][k=32kc+8*(l>>4)+2rr+{0,1}].
__global__ void wpack_k(const float* __restrict__ whh, uint32* __restrict__ wpk) {
  int idx = blockIdx.x * blockDim.x + threadIdx.x;  // < 131072
  int i = idx >> 14;
  int kc = (idx >> 11) & 7;
  int t = (idx >> 2) & 511;
  int rr = idx & 3;
  int w = t >> 6, l = t & 63;
  int lr = 16 * w + (l & 15);
  int R = (lr >> 5) * 256 + 32 * i + (lr & 31);
  int k = 32 * kc + 8 * (l >> 4) + 2 * rr;
  half2_t h;
  h.x = (_Float16)whh[R * 256 + k];
  h.y = (_Float16)whh[R * 256 + k + 1];
  wpk[((i * 8 + kc) * 512 + t) * 4 + rr] = __builtin_bit_cast(uint32, h);
}

// init carried state + board (every launch -> replay-safe).
// Board per group: [parity 2][n 16][pair 128] tagged u64. parity0 = h0, tag 0
// (step-0 want); parity1 = never-match (overwritten by step-0 posts).
__global__ void state_init_k(const float* __restrict__ state, float* __restrict__ cst,
                             uint64* __restrict__ hx) {
  int i = blockIdx.x * blockDim.x + threadIdx.x;  // < 8192
  int ng = i >> 8, j = i & 255;
  cst[i] = state[ng * 512 + 256 + j];
  int grp = ng >> 4, n = ng & 15;
  if (j < 128) {
    half2_t h2;
    h2.x = (_Float16)state[ng * 512 + 2 * j];
    h2.y = (_Float16)state[ng * 512 + 2 * j + 1];
    hx[(size_t)grp * 4096 + n * 128 + j] = (uint64)__builtin_bit_cast(uint32, h2);
  } else {
    hx[(size_t)grp * 4096 + 2048 + n * 128 + (j - 128)] = 0x8000000000000000ull;
  }
}

// xg[8192][1024] = x(chunk rows, cvt bf16 inline) @ w_ih_bf16^T + bias  [R2/R3 verbatim]
__global__ __launch_bounds__(256) void gemm_xg(const float* __restrict__ x,
                                               const unsigned short* __restrict__ wb,
                                               const float* __restrict__ bias,
                                               float* __restrict__ xg, int ch) {
  __shared__ unsigned short As[128 * 40];  // 80B rows (stride = 5*16B, odd*16)
  __shared__ unsigned short Bs[128 * 40];
  const int tid = threadIdx.x;
  const int m0 = blockIdx.y * 128;
  const int g0 = blockIdx.x * 128;
  const int w = tid >> 6;
  const int lane = tid & 63;
  const int wm = (w >> 1) * 64, wn = (w & 1) * 64;
  const int row_l = tid >> 2;  // 0..63
  const int q = tid & 3;
  const int lr = lane & 15, kg = lane >> 4;

  size_t grow[2];
#pragma unroll
  for (int r = 0; r < 2; ++r) {
    int gm = m0 + row_l + 64 * r;
    grow[r] = (size_t)(gm >> 8) * LSTM_T + (size_t)ch * CH + (gm & 255);
  }

  f32x4 acc[4][4];
#pragma unroll
  for (int i = 0; i < 4; ++i)
#pragma unroll
    for (int j = 0; j < 4; ++j) acc[i][j] = (f32x4){0.f, 0.f, 0.f, 0.f};

  for (int kt = 0; kt < 8; ++kt) {
#pragma unroll
    for (int r = 0; r < 2; ++r) {
      int row = row_l + 64 * r;
      const float* ap = x + grow[r] * 256 + kt * 32 + q * 8;
      float4 v0 = *(const float4*)ap;
      float4 v1 = *(const float4*)(ap + 4);
      u16x8 o;
      o[0] = f2bf(v0.x); o[1] = f2bf(v0.y); o[2] = f2bf(v0.z); o[3] = f2bf(v0.w);
      o[4] = f2bf(v1.x); o[5] = f2bf(v1.y); o[6] = f2bf(v1.z); o[7] = f2bf(v1.w);
      *(uint4*)((char*)As + row * 80 + q * 16) = __builtin_bit_cast(uint4, o);
      uint4 bv = *(const uint4*)(wb + (size_t)(g0 + row) * 256 + kt * 32 + q * 8);
      *(uint4*)((char*)Bs + row * 80 + q * 16) = bv;
    }
    __syncthreads();
    bf16x8 af[4], bfr[4];
#pragma unroll
    for (int i = 0; i < 4; ++i)
      af[i] = __builtin_bit_cast(bf16x8, *(const uint4*)((char*)As + (wm + 16 * i + lr) * 80 + kg * 16));
#pragma unroll
    for (int j = 0; j < 4; ++j)
      bfr[j] = __builtin_bit_cast(bf16x8, *(const uint4*)((char*)Bs + (wn + 16 * j + lr) * 80 + kg * 16));
#pragma unroll
    for (int i = 0; i < 4; ++i)
#pragma unroll
      for (int j = 0; j < 4; ++j)
        acc[i][j] = __builtin_amdgcn_mfma_f32_16x16x32_bf16(af[i], bfr[j], acc[i][j], 0, 0, 0);
    __syncthreads();
  }
#pragma unroll
  for (int j = 0; j < 4; ++j) {
    int gc = g0 + wn + 16 * j + lr;
    float bj = bias[gc];
#pragma unroll
    for (int i = 0; i < 4; ++i) {
#pragma unroll
      for (int r = 0; r < 4; ++r) {
        int m = m0 + wm + 16 * i + kg * 4 + r;
        xg[(size_t)m * NG + gc] = acc[i][j][r] + bj;
      }
    }
  }
}

// Recurrent scan: 2 groups x 8 WGs (grid 64, active b&7<2 -> group 0 on XCD0,
// group 1 on XCD1 under round-robin; correctness placement-independent).
// WG (grp, i): units [32i,32i+32) x 4 gates x 16 samples; 64 MFMA/step
// (R4-verified fragments). Exchange: R12-proven tagged-u64 board in XCD-local
// L2; deposit 4 slots/thread; overwrite-safety by post-implies-consumed proof.
__global__ __launch_bounds__(512, 1) void lstm_scan(const float* __restrict__ xg,
                                                    const uint4* __restrict__ wpk4,
                                                    float* __restrict__ cst,
                                                    uint64* __restrict__ hx,
                                                    float* __restrict__ out, int ch) {
  __shared__ uint32 hb[2][16][132];      // h pairs [parity][sample][unit-pair+pad]
  __shared__ float actb[4][32][17];      // gates [q][u_loc][sample]
  __shared__ float ostage[16][16][36];   // h out [step][sample][u_loc+pad]

  const int b = blockIdx.x;
  const int grp = b & 7;
  if (grp >= 2) return;
  const int i = b >> 3;                 // WG's unit block: [32i, 32i+32)
  const int t = threadIdx.x;
  const int w = t >> 6, l = t & 63;
  const int lq = l >> 4, ln = l & 15;   // MFMA: ln = sample col
  const int q = w >> 1;                 // this wave's gate (row-tile w)
  const int cu = t >> 4, cn = t & 15;   // cell identity: unit cu, sample cn

  // A-fragments -> 32 regs (AGPR placement fine: MFMA reads natively)
  uint4 af[8];
#pragma unroll
  for (int kc = 0; kc < 8; ++kc) af[kc] = wpk4[(i * 8 + kc) * 512 + t];

  float c = cst[(grp * 16 + cn) * 256 + 32 * i + cu];

  uint64* board = hx + (size_t)grp * 4096;
  const int gsbase = ch * CH;
  // xg: one float4 per lane per step at rows Rbase..Rbase+3, col sample ln
  const int Rbase = q * 256 + 32 * i + 16 * (w & 1) + 4 * lq;
  const float* xglane = xg + (size_t)(grp * 16 + ln) * CH * NG + Rbase;
  float4 xq = *(const float4*)&xglane[0];

  for (int tt = 0; tt < CH; ++tt) {
    const int s = gsbase + tt;
    const int par = s & 1;
    // deposit all 2048 board slots (4/thread), tag must equal s
    {
      uint64* sp = board + (size_t)par * 2048;
      uint64 v[4];
#pragma unroll
      for (int z = 0; z < 4; ++z)
        v[z] = __hip_atomic_load(&sp[t + 512 * z], __ATOMIC_RELAXED, __HIP_MEMORY_SCOPE_AGENT);
      bool ok;
      do {
        ok = true;
#pragma unroll
        for (int z = 0; z < 4; ++z) ok &= ((uint32)(v[z] >> 32) == (uint32)s);
        if (!ok) {
          __builtin_amdgcn_s_sleep(1);
#pragma unroll
          for (int z = 0; z < 4; ++z)
            v[z] = __hip_atomic_load(&sp[t + 512 * z], __ATOMIC_RELAXED, __HIP_MEMORY_SCOPE_AGENT);
        }
      } while (!ok);
#pragma unroll
      for (int z = 0; z < 4; ++z) {
        int idx = t + 512 * z;
        hb[par][idx >> 7][idx & 127] = (uint32)v[z];
      }
    }
    __syncthreads();                    // BAR-1: h board in LDS
    // prefetch next step's xg
    float4 xn = xq;
    if (tt < CH - 1) xn = *(const float4*)&xglane[(size_t)(tt + 1) * NG];
    // MFMA: 8 k-chunks into one 16x16 acc (B-frags from padded hb rows)
    f32x4 acc = (f32x4){0.f, 0.f, 0.f, 0.f};
#pragma unroll
    for (int kc = 0; kc < 8; ++kc) {
      uint4 bb = *(const uint4*)&hb[par][ln][16 * kc + 4 * lq];
      acc = __builtin_amdgcn_mfma_f32_16x16x32_f16(
          __builtin_bit_cast(f16x8, af[kc]), __builtin_bit_cast(f16x8, bb), acc, 0, 0, 0);
    }
    // activations (wave-uniform gate q); C layout: row=4lq+r, col=ln
#pragma unroll
    for (int r = 0; r < 4; ++r) {
      float pre = acc[r] + ((const float*)&xq)[r];
      float a = (q == 2) ? tanh_fast(pre) : sigm(pre);
      actb[q][16 * (w & 1) + 4 * lq + r][ln] = a;
    }
    xq = xn;
    __syncthreads();                    // BAR-2: gates ready
    // cell: one (unit cu, sample cn) per thread
    {
      float gi = actb[0][cu][cn];
      float gf = actb[1][cu][cn];
      float gg = actb[2][cu][cn];
      float go = actb[3][cu][cn];
      c = gf * c + gi * gg;
      float h = go * tanh_fast(c);
      _Float16 hf = (_Float16)h;
      uint32 hz = (uint32)__builtin_bit_cast(unsigned short, hf);
      ostage[tt & 15][cn][cu] = h;
      uint32 hn = (uint32)__shfl_xor((int)hz, 16, 64);  // partner unit cu^1 (t^16)
      if ((cu & 1) == 0) {  // post pair (u, u+1) of sample cn, tag s+1
        uint64 msg = (uint64)(hz | (hn << 16)) | ((uint64)(uint32)(s + 1) << 32);
        __hip_atomic_store(&board[(size_t)((s + 1) & 1) * 2048 + cn * 128 + 16 * i + (cu >> 1)],
                           msg, __ATOMIC_RELAXED, __HIP_MEMORY_SCOPE_AGENT);
      }
      if (ch == NCH - 1 && tt == CH - 1) {
        float* os = out + (size_t)LSTM_N * LSTM_T * LSTM_H + (grp * 16 + cn) * 512;
        os[32 * i + cu] = h;
        os[256 + 32 * i + cu] = c;
      }
    }
    if ((tt & 15) == 15) {              // flush 16 staged steps
      __syncthreads();
#pragma unroll
      for (int z = 0; z < 4; ++z) {
        int fl = t + 512 * z;
        int sl = fl >> 7, rem = fl & 127;
        int fn = rem >> 3, fq = rem & 7;
        float4 v = *(const float4*)&ostage[sl][fn][4 * fq];
        float* op = out + ((size_t)(grp * 16 + fn) * LSTM_T + (size_t)ch * CH + (tt - 15 + sl)) * LSTM_H
                    + 32 * i + 4 * fq;
        *(float4*)op = v;
      }
    }
  }
  // persist carried c (h carries via board posts)
  cst[(grp * 16 + cn) * 256 + 32 * i + cu] = c;
}

extern "C" void kernel_launch(void* const* d_in, const int* in_sizes, int n_in,
                              void* d_out, int out_size, void* d_ws, size_t ws_size,
                              hipStream_t stream) {
  const float* x   = (const float*)d_in[0];
  const float* st  = (const float*)d_in[1];
  const float* wih = (const float*)d_in[2];
  const float* whh = (const float*)d_in[3];
  const float* bih = (const float*)d_in[4];
  const float* bhh = (const float*)d_in[5];
  float* out = (float*)d_out;
  char* ws = (char*)d_ws;

  float* xg = (float*)(ws + OFF_XG);
  unsigned short* wihb = (unsigned short*)(ws + OFF_WIHB);
  float* bias = (float*)(ws + OFF_BIAS);
  uint32* wpk = (uint32*)(ws + OFF_WPK);
  float* cst = (float*)(ws + OFF_CST);
  uint64* hx = (uint64*)(ws + OFF_HX);

  cvt_bf16_k<<<(NG * LSTM_D / 4 + 255) / 256, 256, 0, stream>>>(wih, wihb, NG * LSTM_D);
  bias_sum_k<<<4, 256, 0, stream>>>(bih, bhh, bias);
  wpack_k<<<512, 256, 0, stream>>>(whh, wpk);
  state_init_k<<<32, 256, 0, stream>>>(st, cst, hx);

  for (int ch = 0; ch < NCH; ++ch) {
    gemm_xg<<<dim3(NG / 128, MCH / 128), 256, 0, stream>>>(x, wihb, bias, xg, ch);
    lstm_scan<<<64, 512, 0, stream>>>(xg, (const uint4*)wpk, cst, hx, out, ch);
  }
}

// Round 15
// 4603.970 us; speedup vs baseline: 1.4708x; 1.4708x over previous
//
#include <hip/hip_runtime.h>

typedef _Float16 half2_t __attribute__((ext_vector_type(2)));
typedef __bf16   bf16x8  __attribute__((ext_vector_type(8)));
typedef float    f32x4   __attribute__((ext_vector_type(4)));
typedef unsigned short u16x8 __attribute__((ext_vector_type(8)));
typedef unsigned int  uint32;
typedef unsigned long long uint64;

#define LSTM_N 32
#define LSTM_T 2048
#define LSTM_D 256
#define LSTM_H 256
#define NG 1024
#define CH 256                    // time-chunk length
#define NCH (LSTM_T / CH)         // 8 chunks
#define MCH (LSTM_N * CH)         // 8192 rows per chunk GEMM

// ---- workspace layout (bytes) ---- (~34.7 MB, R9 layout)
#define OFF_XG   ((size_t)0)
#define SZ_XG    ((size_t)MCH * NG * 4)             // 33,554,432 xg chunk f32
#define OFF_WIHB (OFF_XG + SZ_XG)
#define SZ_WIHB  ((size_t)NG * LSTM_D * 2)          // w_ih bf16
#define OFF_BIAS (OFF_WIHB + SZ_WIHB)
#define SZ_BIAS  ((size_t)4096)
#define OFF_WPK  (OFF_BIAS + SZ_BIAS)
#define SZ_WPK   ((size_t)2 * 512 * 128 * 4)        // 524,288 w_hh f16 pairs (R9 layout)
#define OFF_CST  (OFF_WPK + SZ_WPK)
#define SZ_CST   ((size_t)LSTM_N * 256 * 4)         // c state f32
#define OFF_HST  (OFF_CST + SZ_CST)
#define SZ_HST   ((size_t)LSTM_N * 128 * 4)         // h state f16-pairs (u32)
#define OFF_HX   (OFF_HST + SZ_HST)
#define SZ_HX    ((size_t)LSTM_N * 2 * 2 * 64 * 8)  // 65,536 tagged-u64 exchange slots

#if defined(__has_builtin)
#if __has_builtin(__builtin_amdgcn_fdot2)
#define HAVE_FDOT2 1
#endif
#endif

// PROVEN datapath (R2/R3/R6/R8/R9/R12, absmax 0.0078). Inline-asm v_dot2 is
// numerically WRONG on gfx950 (R5/R7 failed identically) - permanently banned.
__device__ __forceinline__ float fdot2(uint32 w, uint32 h, float acc) {
#ifdef HAVE_FDOT2
  return __builtin_amdgcn_fdot2(__builtin_bit_cast(half2_t, w),
                                __builtin_bit_cast(half2_t, h), acc, false);
#else
  half2_t wv = __builtin_bit_cast(half2_t, w);
  half2_t hv = __builtin_bit_cast(half2_t, h);
  float r = fmaf((float)wv.x, (float)hv.x, acc);
  return fmaf((float)wv.y, (float)hv.y, r);
#endif
}

__device__ __forceinline__ float tanh_fast(float x) { return 2.f / (1.f + __expf(-2.f * x)) - 1.f; }

__device__ __forceinline__ unsigned short f2bf(float f) {
  uint32 u = __builtin_bit_cast(uint32, f);
  uint32 r = (u + 0x7FFFu + ((u >> 16) & 1u)) >> 16;
  return (unsigned short)r;
}

// reduce-scatter over 8 kappa-lanes (masks 4/2/1 -> in-wave). R9-proven.
__device__ __forceinline__ float bfly8(const float a[8], int kap) {
  float k0[4], g0[4];
  const bool b4 = (kap & 4) != 0;
#pragma unroll
  for (int v = 0; v < 4; ++v) {
    k0[v] = b4 ? a[v + 4] : a[v];
    g0[v] = b4 ? a[v] : a[v + 4];
  }
#pragma unroll
  for (int v = 0; v < 4; ++v) k0[v] += __shfl_xor(g0[v], 4, 64);
  float k1[2], g1[2];
  const bool b2 = (kap & 2) != 0;
#pragma unroll
  for (int v = 0; v < 2; ++v) {
    k1[v] = b2 ? k0[v + 2] : k0[v];
    g1[v] = b2 ? k0[v] : k0[v + 2];
  }
#pragma unroll
  for (int v = 0; v < 2; ++v) k1[v] += __shfl_xor(g1[v], 2, 64);
  const bool b1 = (kap & 1) != 0;
  float k2 = b1 ? k1[1] : k1[0];
  float g2 = b1 ? k1[0] : k1[1];
  return k2 + __shfl_xor(g2, 1, 64);
}

// ---------------- kernels (cvt/bias/wpack/state_init/gemm = R9 verbatim) ----------------

__global__ void cvt_bf16_k(const float* __restrict__ src, unsigned short* __restrict__ dst, int n) {
  int i = blockIdx.x * blockDim.x + threadIdx.x;
  if (4 * i + 3 < n) {
    float4 v = ((const float4*)src)[i];
    ushort4 o;
    o.x = f2bf(v.x); o.y = f2bf(v.y); o.z = f2bf(v.z); o.w = f2bf(v.w);
    ((ushort4*)dst)[i] = o;
  }
}

__global__ void bias_sum_k(const float* __restrict__ bih, const float* __restrict__ bhh,
                           float* __restrict__ bias) {
  int g = blockIdx.x * blockDim.x + threadIdx.x;
  if (g < NG) bias[g] = bih[g] + bhh[g];
}

// Pack w_hh f32[1024][256] -> f16-pair images for scan WG-half p, thread t.
// Thread t: w=t>>6, l=t&63, q=l>>4, b3=(l>>3)&1, kap=l&7.
// wr[j*16+m]: row = q*256+128p+16w+8b3+j (j=0..7);
//             k = m<8 ? 128p+16kap+2m : 128(1-p)+16kap+2(m-8).   [R9 verbatim]
__global__ void wpack_k(const float* __restrict__ whh, uint32* __restrict__ wpk) {
  int e = blockIdx.x * blockDim.x + threadIdx.x;  // < 131072
  int p = e >> 16;
  int i128 = (e >> 9) & 127;
  int t = e & 511;
  int j = i128 >> 4, m = i128 & 15;
  int w = t >> 6, l = t & 63;
  int q = l >> 4, b3 = (l >> 3) & 1, kap = l & 7;
  int row = q * 256 + 128 * p + 16 * w + 8 * b3 + j;
  int k = (m < 8) ? (128 * p + 16 * kap + 2 * m)
                  : (128 * (1 - p) + 16 * kap + 2 * (m - 8));
  half2_t h;
  h.x = (_Float16)whh[row * 256 + k];
  h.y = (_Float16)whh[row * 256 + k + 1];
  wpk[((i128 >> 2) * 1024 + p * 512 + t) * 4 + (i128 & 3)] = __builtin_bit_cast(uint32, h);
}

// init carried state + zero exchange tags (every launch -> replay-safe) [R9 verbatim]
__global__ void state_init_k(const float* __restrict__ state, float* __restrict__ cst,
                             uint32* __restrict__ hst, uint64* __restrict__ hx) {
  int i = blockIdx.x * blockDim.x + threadIdx.x;  // < 8192
  int n = i >> 8, j = i & 255;
  cst[i] = state[n * 512 + 256 + j];
  if ((j & 1) == 0) {
    half2_t h2;
    h2.x = (_Float16)state[n * 512 + j];
    h2.y = (_Float16)state[n * 512 + j + 1];
    hst[(n << 7) + (j >> 1)] = __builtin_bit_cast(uint32, h2);
  }
  hx[i] = 0ull;
}

// xg[8192][1024] = x(chunk rows, cvt bf16 inline) @ w_ih_bf16^T + bias  [R2/R3 verbatim]
__global__ __launch_bounds__(256) void gemm_xg(const float* __restrict__ x,
                                               const unsigned short* __restrict__ wb,
                                               const float* __restrict__ bias,
                                               float* __restrict__ xg, int ch) {
  __shared__ unsigned short As[128 * 40];  // 80B rows (stride = 5*16B, odd*16)
  __shared__ unsigned short Bs[128 * 40];
  const int tid = threadIdx.x;
  const int m0 = blockIdx.y * 128;
  const int g0 = blockIdx.x * 128;
  const int w = tid >> 6;
  const int lane = tid & 63;
  const int wm = (w >> 1) * 64, wn = (w & 1) * 64;
  const int row_l = tid >> 2;  // 0..63
  const int q = tid & 3;
  const int lr = lane & 15, kg = lane >> 4;

  size_t grow[2];
#pragma unroll
  for (int r = 0; r < 2; ++r) {
    int gm = m0 + row_l + 64 * r;
    grow[r] = (size_t)(gm >> 8) * LSTM_T + (size_t)ch * CH + (gm & 255);
  }

  f32x4 acc[4][4];
#pragma unroll
  for (int i = 0; i < 4; ++i)
#pragma unroll
    for (int j = 0; j < 4; ++j) acc[i][j] = (f32x4){0.f, 0.f, 0.f, 0.f};

  for (int kt = 0; kt < 8; ++kt) {
#pragma unroll
    for (int r = 0; r < 2; ++r) {
      int row = row_l + 64 * r;
      const float* ap = x + grow[r] * 256 + kt * 32 + q * 8;
      float4 v0 = *(const float4*)ap;
      float4 v1 = *(const float4*)(ap + 4);
      u16x8 o;
      o[0] = f2bf(v0.x); o[1] = f2bf(v0.y); o[2] = f2bf(v0.z); o[3] = f2bf(v0.w);
      o[4] = f2bf(v1.x); o[5] = f2bf(v1.y); o[6] = f2bf(v1.z); o[7] = f2bf(v1.w);
      *(uint4*)((char*)As + row * 80 + q * 16) = __builtin_bit_cast(uint4, o);
      uint4 bv = *(const uint4*)(wb + (size_t)(g0 + row) * 256 + kt * 32 + q * 8);
      *(uint4*)((char*)Bs + row * 80 + q * 16) = bv;
    }
    __syncthreads();
    bf16x8 af[4], bfr[4];
#pragma unroll
    for (int i = 0; i < 4; ++i)
      af[i] = __builtin_bit_cast(bf16x8, *(const uint4*)((char*)As + (wm + 16 * i + lr) * 80 + kg * 16));
#pragma unroll
    for (int j = 0; j < 4; ++j)
      bfr[j] = __builtin_bit_cast(bf16x8, *(const uint4*)((char*)Bs + (wn + 16 * j + lr) * 80 + kg * 16));
#pragma unroll
    for (int i = 0; i < 4; ++i)
#pragma unroll
      for (int j = 0; j < 4; ++j)
        acc[i][j] = __builtin_amdgcn_mfma_f32_16x16x32_bf16(af[i], bfr[j], acc[i][j], 0, 0, 0);
    __syncthreads();
  }
#pragma unroll
  for (int j = 0; j < 4; ++j) {
    int gc = g0 + wn + 16 * j + lr;
    float bj = bias[gc];
#pragma unroll
    for (int i = 0; i < 4; ++i) {
#pragma unroll
      for (int r = 0; r < 4; ++r) {
        int m = m0 + wm + 16 * i + kg * 4 + r;
        xg[(size_t)m * NG + gc] = acc[i][j][r] + bj;
      }
    }
  }
}

// Recurrent scan: R9 datapath x 2 samples per WG (A=n, B=n+16; same weights).
// 32 WGs (n=b&15, p=b>>4; pair (b,b+16) same XCD). Per iteration: phase A
// then phase B, each an exact R9 step. A's post is consumed after a full
// phase B (~1300cy > L) -> exchange latency leaves the serial chain. One
// barrier per phase. Hazard audit: hpeerX written (pollers) then BAR-X then
// read; rewritten next iter after the OTHER phase's barrier. hownX[par^1]
// written at phase-X end, read next iter phase-X after the other barrier.
__global__ __launch_bounds__(512, 1) void lstm_scan(const float* __restrict__ xg,
                                                    const uint4* __restrict__ wpk4,
                                                    float* __restrict__ cst,
                                                    uint32* __restrict__ hst,
                                                    uint64* __restrict__ hx,
                                                    float* __restrict__ out, int ch) {
  __shared__ uint32 hownA[2][64], hownB[2][64];  // own-half h, parity dbuf
  __shared__ uint32 hpeerA[64], hpeerB[64];      // peer-half deposits
  __shared__ float ostage[2][16][128];           // [sample][step][unit]

  const int b = blockIdx.x;
  const int n = b & 15;
  const int p = b >> 4;
  const int nA = n, nB = n + 16;
  const int t = threadIdx.x;
  const int w = t >> 6, l = t & 63;
  const int q = l >> 4, kap = l & 7;
  const int u = 16 * w + (l & 15);
  const int R = q * 256 + 128 * p + u;

  // weights -> 128 regs, shared by both samples (AGPR split accepted)
  uint32 wr[128];
#pragma unroll
  for (int ig = 0; ig < 32; ++ig) {
    uint4 v = wpk4[ig * 1024 + p * 512 + t];
    wr[4 * ig + 0] = v.x; wr[4 * ig + 1] = v.y; wr[4 * ig + 2] = v.z; wr[4 * ig + 3] = v.w;
  }
  float cA = cst[nA * 256 + 128 * p + u];
  float cB = cst[nB * 256 + 128 * p + u];
  if (t < 64) {
    hownA[0][t] = hst[nA * 128 + 64 * p + t];
    hpeerA[t]   = hst[nA * 128 + 64 * (1 - p) + t];
    hownB[0][t] = hst[nB * 128 + 64 * p + t];
    hpeerB[t]   = hst[nB * 128 + 64 * (1 - p) + t];
  }
  __syncthreads();

  const float* xgA = xg + (size_t)nA * CH * NG;
  const float* xgB = xg + (size_t)nB * CH * NG;
  float* outA = out + ((size_t)nA * LSTM_T + (size_t)ch * CH) * LSTM_H;
  float* outB = out + ((size_t)nB * LSTM_T + (size_t)ch * CH) * LSTM_H;
  uint64* hxA_own  = hx + (size_t)(nA * 2 + p) * 128;
  uint64* hxA_peer = hx + (size_t)(nA * 2 + (1 - p)) * 128;
  uint64* hxB_own  = hx + (size_t)(nB * 2 + p) * 128;
  uint64* hxB_peer = hx + (size_t)(nB * 2 + (1 - p)) * 128;
  const int gsbase = ch * CH;

  float xcA = xgA[R];
  float xcB = xgB[R];

  for (int tt = 0; tt < CH; ++tt) {
    const uint32 gs = (uint32)(gsbase + tt);
    // ======== phase A (sample nA) — exact R9 step ========
    {
      float xnext = (tt < CH - 1) ? xgA[(size_t)(tt + 1) * NG + R] : 0.f;
      uint32 hro[8];
      *(uint4*)&hro[0] = *(const uint4*)&hownA[tt & 1][8 * kap];
      *(uint4*)&hro[4] = *(const uint4*)&hownA[tt & 1][8 * kap + 4];
      float acc[8];
#pragma unroll
      for (int j = 0; j < 8; ++j) {
        float a = 0.f;
#pragma unroll
        for (int m = 0; m < 8; ++m) a = fdot2(wr[j * 16 + m], hro[m], a);
        acc[j] = a;
      }
      if (tt > 0 && t < 64) {  // wave-0 pollers: 1 tagged slot each
        uint64 v;
        do {
          v = __hip_atomic_load(&hxA_peer[(size_t)(tt & 1) * 64 + t],
                                __ATOMIC_RELAXED, __HIP_MEMORY_SCOPE_AGENT);
        } while ((uint32)(v >> 32) != gs);
        hpeerA[t] = (uint32)v;
      }
      __syncthreads();                  // BAR-A
      uint32 hrp[8];
      *(uint4*)&hrp[0] = *(const uint4*)&hpeerA[8 * kap];
      *(uint4*)&hrp[4] = *(const uint4*)&hpeerA[8 * kap + 4];
#pragma unroll
      for (int j = 0; j < 8; ++j) {
        float a = acc[j];
#pragma unroll
        for (int m = 0; m < 8; ++m) a = fdot2(wr[j * 16 + 8 + m], hrp[m], a);
        acc[j] = a;
      }
      float s = bfly8(acc, kap);
      float pre = s + xcA;
      xcA = xnext;
      float z = (q == 2) ? (2.f * pre) : pre;
      float sg = 1.f / (1.f + __expf(-z));
      float a_own = (q == 2) ? (2.f * sg - 1.f) : sg;
      float a1 = __shfl_xor(a_own, 16, 64);
      float a2 = __shfl_xor(a_own, 32, 64);
      float a3 = __shfl_xor(a1, 32, 64);
      float gi = (q == 0) ? a_own : ((q == 1) ? a1 : ((q == 2) ? a2 : a3));
      float gf = (q == 1) ? a_own : ((q == 0) ? a1 : ((q == 3) ? a2 : a3));
      float gg = (q == 2) ? a_own : ((q == 3) ? a1 : ((q == 0) ? a2 : a3));
      float go = (q == 3) ? a_own : ((q == 2) ? a1 : ((q == 1) ? a2 : a3));
      cA = gf * cA + gi * gg;
      float h = go * tanh_fast(cA);
      _Float16 hf16 = (_Float16)h;
      uint32 hz = (uint32)__builtin_bit_cast(unsigned short, hf16);
      uint32 hn = (uint32)__shfl_xor((int)hz, 1, 64);
      if (q == 0) {
        ((unsigned short*)&hownA[(tt + 1) & 1][0])[u] = (unsigned short)hz;
        ostage[0][tt & 15][u] = h;
        if (tt < CH - 1 && (l & 1) == 0) {
          uint64 msg = (uint64)(hz | (hn << 16)) | ((uint64)(gs + 1) << 32);
          __hip_atomic_store(&hxA_own[(size_t)((tt + 1) & 1) * 64 + (u >> 1)], msg,
                             __ATOMIC_RELAXED, __HIP_MEMORY_SCOPE_AGENT);
        }
        if (ch == NCH - 1 && tt == CH - 1) {
          float* os = out + (size_t)LSTM_N * LSTM_T * LSTM_H + nA * 512;
          os[128 * p + u] = h;
          os[256 + 128 * p + u] = cA;
        }
      }
    }
    // ======== phase B (sample nB) — A's post hides under this ========
    {
      float xnext = (tt < CH - 1) ? xgB[(size_t)(tt + 1) * NG + R] : 0.f;
      uint32 hro[8];
      *(uint4*)&hro[0] = *(const uint4*)&hownB[tt & 1][8 * kap];
      *(uint4*)&hro[4] = *(const uint4*)&hownB[tt & 1][8 * kap + 4];
      float acc[8];
#pragma unroll
      for (int j = 0; j < 8; ++j) {
        float a = 0.f;
#pragma unroll
        for (int m = 0; m < 8; ++m) a = fdot2(wr[j * 16 + m], hro[m], a);
        acc[j] = a;
      }
      if (tt > 0 && t >= 64 && t < 128) {  // wave-1 pollers
        int sl = t - 64;
        uint64 v;
        do {
          v = __hip_atomic_load(&hxB_peer[(size_t)(tt & 1) * 64 + sl],
                                __ATOMIC_RELAXED, __HIP_MEMORY_SCOPE_AGENT);
        } while ((uint32)(v >> 32) != gs);
        hpeerB[sl] = (uint32)v;
      }
      __syncthreads();                  // BAR-B
      uint32 hrp[8];
      *(uint4*)&hrp[0] = *(const uint4*)&hpeerB[8 * kap];
      *(uint4*)&hrp[4] = *(const uint4*)&hpeerB[8 * kap + 4];
#pragma unroll
      for (int j = 0; j < 8; ++j) {
        float a = acc[j];
#pragma unroll
        for (int m = 0; m < 8; ++m) a = fdot2(wr[j * 16 + 8 + m], hrp[m], a);
        acc[j] = a;
      }
      float s = bfly8(acc, kap);
      float pre = s + xcB;
      xcB = xnext;
      float z = (q == 2) ? (2.f * pre) : pre;
      float sg = 1.f / (1.f + __expf(-z));
      float a_own = (q == 2) ? (2.f * sg - 1.f) : sg;
      float a1 = __shfl_xor(a_own, 16, 64);
      float a2 = __shfl_xor(a_own, 32, 64);
      float a3 = __shfl_xor(a1, 32, 64);
      float gi = (q == 0) ? a_own : ((q == 1) ? a1 : ((q == 2) ? a2 : a3));
      float gf = (q == 1) ? a_own : ((q == 0) ? a1 : ((q == 3) ? a2 : a3));
      float gg = (q == 2) ? a_own : ((q == 3) ? a1 : ((q == 0) ? a2 : a3));
      float go = (q == 3) ? a_own : ((q == 2) ? a1 : ((q == 1) ? a2 : a3));
      cB = gf * cB + gi * gg;
      float h = go * tanh_fast(cB);
      _Float16 hf16 = (_Float16)h;
      uint32 hz = (uint32)__builtin_bit_cast(unsigned short, hf16);
      uint32 hn = (uint32)__shfl_xor((int)hz, 1, 64);
      if (q == 0) {
        ((unsigned short*)&hownB[(tt + 1) & 1][0])[u] = (unsigned short)hz;
        ostage[1][tt & 15][u] = h;
        if (tt < CH - 1 && (l & 1) == 0) {
          uint64 msg = (uint64)(hz | (hn << 16)) | ((uint64)(gs + 1) << 32);
          __hip_atomic_store(&hxB_own[(size_t)((tt + 1) & 1) * 64 + (u >> 1)], msg,
                             __ATOMIC_RELAXED, __HIP_MEMORY_SCOPE_AGENT);
        }
        if (ch == NCH - 1 && tt == CH - 1) {
          float* os = out + (size_t)LSTM_N * LSTM_T * LSTM_H + nB * 512;
          os[128 * p + u] = h;
          os[256 + 128 * p + u] = cB;
        }
      }
    }
    if ((tt & 15) == 15) {              // flush 16 staged steps, both samples
      __syncthreads();                  // ostage writes visible
      int sl = t >> 5, g4 = t & 31;     // 512 float4 per sample
      float4 vA = *(const float4*)&ostage[0][sl][4 * g4];
      *(float4*)&outA[(size_t)(tt - 15 + sl) * LSTM_H + 128 * p + 4 * g4] = vA;
      float4 vB = *(const float4*)&ostage[1][sl][4 * g4];
      *(float4*)&outB[(size_t)(tt - 15 + sl) * LSTM_H + 128 * p + 4 * g4] = vB;
    }
  }
  // persist carried state (CH even -> final h in hown[0])
  if (q == 0) {
    cst[nA * 256 + 128 * p + u] = cA;
    cst[nB * 256 + 128 * p + u] = cB;
  }
  if (t < 64) {
    hst[nA * 128 + 64 * p + t] = hownA[0][t];
    hst[nB * 128 + 64 * p + t] = hownB[0][t];
  }
}

extern "C" void kernel_launch(void* const* d_in, const int* in_sizes, int n_in,
                              void* d_out, int out_size, void* d_ws, size_t ws_size,
                              hipStream_t stream) {
  const float* x   = (const float*)d_in[0];
  const float* st  = (const float*)d_in[1];
  const float* wih = (const float*)d_in[2];
  const float* whh = (const float*)d_in[3];
  const float* bih = (const float*)d_in[4];
  const float* bhh = (const float*)d_in[5];
  float* out = (float*)d_out;
  char* ws = (char*)d_ws;

  float* xg = (float*)(ws + OFF_XG);
  unsigned short* wihb = (unsigned short*)(ws + OFF_WIHB);
  float* bias = (float*)(ws + OFF_BIAS);
  uint32* wpk = (uint32*)(ws + OFF_WPK);
  float* cst = (float*)(ws + OFF_CST);
  uint32* hst = (uint32*)(ws + OFF_HST);
  uint64* hx = (uint64*)(ws + OFF_HX);

  cvt_bf16_k<<<(NG * LSTM_D / 4 + 255) / 256, 256, 0, stream>>>(wih, wihb, NG * LSTM_D);
  bias_sum_k<<<4, 256, 0, stream>>>(bih, bhh, bias);
  wpack_k<<<512, 256, 0, stream>>>(whh, wpk);
  state_init_k<<<32, 256, 0, stream>>>(st, cst, hst, hx);

  for (int ch = 0; ch < NCH; ++ch) {
    gemm_xg<<<dim3(NG / 128, MCH / 128), 256, 0, stream>>>(x, wihb, bias, xg, ch);
    lstm_scan<<<32, 512, 0, stream>>>(xg, (const uint4*)wpk, cst, hst, hx, out, ch);
  }
}

// Round 16
// 3445.959 us; speedup vs baseline: 1.9651x; 1.3360x over previous
//
#include <hip/hip_runtime.h>

typedef _Float16 half2_t __attribute__((ext_vector_type(2)));
typedef __bf16   bf16x8  __attribute__((ext_vector_type(8)));
typedef float    f32x4   __attribute__((ext_vector_type(4)));
typedef unsigned short u16x8 __attribute__((ext_vector_type(8)));
typedef unsigned int  uint32;
typedef unsigned long long uint64;

#define LSTM_N 32
#define LSTM_T 2048
#define LSTM_D 256
#define LSTM_H 256
#define NG 1024
#define CH 256                    // time-chunk length
#define NCH (LSTM_T / CH)         // 8 chunks
#define MCH (LSTM_N * CH)         // 8192 rows per chunk GEMM

// ---- workspace layout (bytes) ---- (~34.7 MB, R9 layout)
#define OFF_XG   ((size_t)0)
#define SZ_XG    ((size_t)MCH * NG * 4)             // 33,554,432 xg chunk f32
#define OFF_WIHB (OFF_XG + SZ_XG)
#define SZ_WIHB  ((size_t)NG * LSTM_D * 2)          // w_ih bf16
#define OFF_BIAS (OFF_WIHB + SZ_WIHB)
#define SZ_BIAS  ((size_t)4096)
#define OFF_WPK  (OFF_BIAS + SZ_BIAS)
#define SZ_WPK   ((size_t)2 * 512 * 128 * 4)        // 524,288 w_hh f16 pairs (R9 layout)
#define OFF_CST  (OFF_WPK + SZ_WPK)
#define SZ_CST   ((size_t)LSTM_N * 256 * 4)         // c state f32
#define OFF_HST  (OFF_CST + SZ_CST)
#define SZ_HST   ((size_t)LSTM_N * 128 * 4)         // h state f16-pairs (u32)
#define OFF_HX   (OFF_HST + SZ_HST)
#define SZ_HX    ((size_t)LSTM_N * 2 * 2 * 64 * 8)  // 65,536 tagged-u64 exchange slots

#if defined(__has_builtin)
#if __has_builtin(__builtin_amdgcn_fdot2)
#define HAVE_FDOT2 1
#endif
#endif

// PROVEN datapath (R2/R3/R6/R8/R9/R12, absmax 0.0078). Inline-asm v_dot2 is
// numerically WRONG on gfx950 (R5/R7 failed identically) - permanently banned.
__device__ __forceinline__ float fdot2(uint32 w, uint32 h, float acc) {
#ifdef HAVE_FDOT2
  return __builtin_amdgcn_fdot2(__builtin_bit_cast(half2_t, w),
                                __builtin_bit_cast(half2_t, h), acc, false);
#else
  half2_t wv = __builtin_bit_cast(half2_t, w);
  half2_t hv = __builtin_bit_cast(half2_t, h);
  float r = fmaf((float)wv.x, (float)hv.x, acc);
  return fmaf((float)wv.y, (float)hv.y, r);
#endif
}

__device__ __forceinline__ float tanh_fast(float x) { return 2.f / (1.f + __expf(-2.f * x)) - 1.f; }

__device__ __forceinline__ unsigned short f2bf(float f) {
  uint32 u = __builtin_bit_cast(uint32, f);
  uint32 r = (u + 0x7FFFu + ((u >> 16) & 1u)) >> 16;
  return (unsigned short)r;
}

// LDS-only barrier (T4 lesson): __syncthreads drains vmcnt(0) too, which
// serializes the in-flight xg prefetch (~600-900cy HBM) and exchange post
// (~300cy L2) into every step. All cross-wave hazards in this kernel are
// LDS -> lgkmcnt(0) suffices. sched_barrier(0) pins against hoisting (rule #18).
__device__ __forceinline__ void bar_lds() {
  asm volatile("s_waitcnt lgkmcnt(0)" ::: "memory");
  __builtin_amdgcn_s_barrier();
  __builtin_amdgcn_sched_barrier(0);
}

// reduce-scatter over 8 kappa-lanes (masks 4/2/1 -> in-wave). R9-proven.
__device__ __forceinline__ float bfly8(const float a[8], int kap) {
  float k0[4], g0[4];
  const bool b4 = (kap & 4) != 0;
#pragma unroll
  for (int v = 0; v < 4; ++v) {
    k0[v] = b4 ? a[v + 4] : a[v];
    g0[v] = b4 ? a[v] : a[v + 4];
  }
#pragma unroll
  for (int v = 0; v < 4; ++v) k0[v] += __shfl_xor(g0[v], 4, 64);
  float k1[2], g1[2];
  const bool b2 = (kap & 2) != 0;
#pragma unroll
  for (int v = 0; v < 2; ++v) {
    k1[v] = b2 ? k0[v + 2] : k0[v];
    g1[v] = b2 ? k0[v] : k0[v + 2];
  }
#pragma unroll
  for (int v = 0; v < 2; ++v) k1[v] += __shfl_xor(g1[v], 2, 64);
  const bool b1 = (kap & 1) != 0;
  float k2 = b1 ? k1[1] : k1[0];
  float g2 = b1 ? k1[0] : k1[1];
  return k2 + __shfl_xor(g2, 1, 64);
}

// ---------------- kernels (cvt/bias/wpack/state_init/gemm = R9 verbatim) ----------------

__global__ void cvt_bf16_k(const float* __restrict__ src, unsigned short* __restrict__ dst, int n) {
  int i = blockIdx.x * blockDim.x + threadIdx.x;
  if (4 * i + 3 < n) {
    float4 v = ((const float4*)src)[i];
    ushort4 o;
    o.x = f2bf(v.x); o.y = f2bf(v.y); o.z = f2bf(v.z); o.w = f2bf(v.w);
    ((ushort4*)dst)[i] = o;
  }
}

__global__ void bias_sum_k(const float* __restrict__ bih, const float* __restrict__ bhh,
                           float* __restrict__ bias) {
  int g = blockIdx.x * blockDim.x + threadIdx.x;
  if (g < NG) bias[g] = bih[g] + bhh[g];
}

// Pack w_hh f32[1024][256] -> f16-pair images for scan WG-half p, thread t.
// Thread t: w=t>>6, l=t&63, q=l>>4, b3=(l>>3)&1, kap=l&7.
// wr[j*16+m]: row = q*256+128p+16w+8b3+j (j=0..7);
//             k = m<8 ? 128p+16kap+2m : 128(1-p)+16kap+2(m-8).   [R9 verbatim]
__global__ void wpack_k(const float* __restrict__ whh, uint32* __restrict__ wpk) {
  int e = blockIdx.x * blockDim.x + threadIdx.x;  // < 131072
  int p = e >> 16;
  int i128 = (e >> 9) & 127;
  int t = e & 511;
  int j = i128 >> 4, m = i128 & 15;
  int w = t >> 6, l = t & 63;
  int q = l >> 4, b3 = (l >> 3) & 1, kap = l & 7;
  int row = q * 256 + 128 * p + 16 * w + 8 * b3 + j;
  int k = (m < 8) ? (128 * p + 16 * kap + 2 * m)
                  : (128 * (1 - p) + 16 * kap + 2 * (m - 8));
  half2_t h;
  h.x = (_Float16)whh[row * 256 + k];
  h.y = (_Float16)whh[row * 256 + k + 1];
  wpk[((i128 >> 2) * 1024 + p * 512 + t) * 4 + (i128 & 3)] = __builtin_bit_cast(uint32, h);
}

// init carried state + zero exchange tags (every launch -> replay-safe) [R9 verbatim]
__global__ void state_init_k(const float* __restrict__ state, float* __restrict__ cst,
                             uint32* __restrict__ hst, uint64* __restrict__ hx) {
  int i = blockIdx.x * blockDim.x + threadIdx.x;  // < 8192
  int n = i >> 8, j = i & 255;
  cst[i] = state[n * 512 + 256 + j];
  if ((j & 1) == 0) {
    half2_t h2;
    h2.x = (_Float16)state[n * 512 + j];
    h2.y = (_Float16)state[n * 512 + j + 1];
    hst[(n << 7) + (j >> 1)] = __builtin_bit_cast(uint32, h2);
  }
  hx[i] = 0ull;
}

// xg[8192][1024] = x(chunk rows, cvt bf16 inline) @ w_ih_bf16^T + bias  [R2/R3 verbatim]
__global__ __launch_bounds__(256) void gemm_xg(const float* __restrict__ x,
                                               const unsigned short* __restrict__ wb,
                                               const float* __restrict__ bias,
                                               float* __restrict__ xg, int ch) {
  __shared__ unsigned short As[128 * 40];  // 80B rows (stride = 5*16B, odd*16)
  __shared__ unsigned short Bs[128 * 40];
  const int tid = threadIdx.x;
  const int m0 = blockIdx.y * 128;
  const int g0 = blockIdx.x * 128;
  const int w = tid >> 6;
  const int lane = tid & 63;
  const int wm = (w >> 1) * 64, wn = (w & 1) * 64;
  const int row_l = tid >> 2;  // 0..63
  const int q = tid & 3;
  const int lr = lane & 15, kg = lane >> 4;

  size_t grow[2];
#pragma unroll
  for (int r = 0; r < 2; ++r) {
    int gm = m0 + row_l + 64 * r;
    grow[r] = (size_t)(gm >> 8) * LSTM_T + (size_t)ch * CH + (gm & 255);
  }

  f32x4 acc[4][4];
#pragma unroll
  for (int i = 0; i < 4; ++i)
#pragma unroll
    for (int j = 0; j < 4; ++j) acc[i][j] = (f32x4){0.f, 0.f, 0.f, 0.f};

  for (int kt = 0; kt < 8; ++kt) {
#pragma unroll
    for (int r = 0; r < 2; ++r) {
      int row = row_l + 64 * r;
      const float* ap = x + grow[r] * 256 + kt * 32 + q * 8;
      float4 v0 = *(const float4*)ap;
      float4 v1 = *(const float4*)(ap + 4);
      u16x8 o;
      o[0] = f2bf(v0.x); o[1] = f2bf(v0.y); o[2] = f2bf(v0.z); o[3] = f2bf(v0.w);
      o[4] = f2bf(v1.x); o[5] = f2bf(v1.y); o[6] = f2bf(v1.z); o[7] = f2bf(v1.w);
      *(uint4*)((char*)As + row * 80 + q * 16) = __builtin_bit_cast(uint4, o);
      uint4 bv = *(const uint4*)(wb + (size_t)(g0 + row) * 256 + kt * 32 + q * 8);
      *(uint4*)((char*)Bs + row * 80 + q * 16) = bv;
    }
    __syncthreads();
    bf16x8 af[4], bfr[4];
#pragma unroll
    for (int i = 0; i < 4; ++i)
      af[i] = __builtin_bit_cast(bf16x8, *(const uint4*)((char*)As + (wm + 16 * i + lr) * 80 + kg * 16));
#pragma unroll
    for (int j = 0; j < 4; ++j)
      bfr[j] = __builtin_bit_cast(bf16x8, *(const uint4*)((char*)Bs + (wn + 16 * j + lr) * 80 + kg * 16));
#pragma unroll
    for (int i = 0; i < 4; ++i)
#pragma unroll
      for (int j = 0; j < 4; ++j)
        acc[i][j] = __builtin_amdgcn_mfma_f32_16x16x32_bf16(af[i], bfr[j], acc[i][j], 0, 0, 0);
    __syncthreads();
  }
#pragma unroll
  for (int j = 0; j < 4; ++j) {
    int gc = g0 + wn + 16 * j + lr;
    float bj = bias[gc];
#pragma unroll
    for (int i = 0; i < 4; ++i) {
#pragma unroll
      for (int r = 0; r < 4; ++r) {
        int m = m0 + wm + 16 * i + kg * 4 + r;
        xg[(size_t)m * NG + gc] = acc[i][j][r] + bj;
      }
    }
  }
}

// Recurrent scan: R9 EXACT datapath/protocol with two latency cuts:
// (1) barriers drain lgkmcnt only (bar_lds) - xg prefetch and exchange post
//     stay in flight across barriers instead of serializing into them;
// (2) the exchange post fires AFTER BAR-2, so its L2 store latency never
//     gates a barrier drain.
// Thread t: kap=t&7, q=(t&63)>>4, u=16*(t>>6)+(t&15), row R=q*256+128p+u.
__global__ __launch_bounds__(512, 1) void lstm_scan(const float* __restrict__ xg,
                                                    const uint4* __restrict__ wpk4,
                                                    float* __restrict__ cst,
                                                    uint32* __restrict__ hst,
                                                    uint64* __restrict__ hx,
                                                    float* __restrict__ out, int ch) {
  __shared__ uint32 hown[2][64];      // own-half h f16-pairs, parity per step
  __shared__ uint32 hpeer[64];        // peer-half deposit (single buffer)
  __shared__ float ostage[16][128];   // h staging, flushed every 16 steps

  const int b = blockIdx.x;
  const int n = b & 31;
  const int p = b >> 5;
  const int t = threadIdx.x;
  const int w = t >> 6, l = t & 63;
  const int q = l >> 4, kap = l & 7;
  const int u = 16 * w + (l & 15);      // unit within half
  const int R = q * 256 + 128 * p + u;  // finalized gate row

  // weights -> 128 regs (AGPR split accepted; builtin fdot2 pays the copy)
  uint32 wr[128];
#pragma unroll
  for (int ig = 0; ig < 32; ++ig) {
    uint4 v = wpk4[ig * 1024 + p * 512 + t];
    wr[4 * ig + 0] = v.x; wr[4 * ig + 1] = v.y; wr[4 * ig + 2] = v.z; wr[4 * ig + 3] = v.w;
  }
  float c = cst[n * 256 + 128 * p + u];   // 4-way redundant (broadcast load)
  if (t < 64) {
    hown[0][t] = hst[n * 128 + 64 * p + t];
    hpeer[t]   = hst[n * 128 + 64 * (1 - p) + t];  // step-0 peer half
  }
  __syncthreads();

  const float* xgn = xg + (size_t)n * CH * NG;
  float* outb = out + ((size_t)n * LSTM_T + (size_t)ch * CH) * LSTM_H;
  uint64* hx_own  = hx + (size_t)(n * 2 + p) * 128;
  uint64* hx_peer = hx + (size_t)(n * 2 + (1 - p)) * 128;
  const int gsbase = ch * CH;

  float xcur = xgn[R];

  for (int tt = 0; tt < CH; ++tt) {
    const uint32 gs = (uint32)(gsbase + tt);
    // xg prefetch for next step (stays in flight across bar_lds - no drain)
    float xnext = (tt < CH - 1) ? xgn[(size_t)(tt + 1) * NG + R] : 0.f;
    // own h-slice (broadcast LDS reads, parity buffer)
    uint32 hro[8];
    *(uint4*)&hro[0] = *(const uint4*)&hown[tt & 1][8 * kap];
    *(uint4*)&hro[4] = *(const uint4*)&hown[tt & 1][8 * kap + 4];
    // own-half partial dots FIRST (8 rows x 8 pairs) - overlaps peer posting
    float acc[8];
#pragma unroll
    for (int j = 0; j < 8; ++j) {
      float a = 0.f;
#pragma unroll
      for (int m = 0; m < 8; ++m) a = fdot2(wr[j * 16 + m], hro[m], a);
      acc[j] = a;
    }
    // designated pollers: 1 tagged slot each (R3/R9-proven protocol, relaxed)
    if (tt > 0 && t < 64) {
      uint64 v;
      do {
        v = __hip_atomic_load(&hx_peer[(size_t)(tt & 1) * 64 + t],
                              __ATOMIC_RELAXED, __HIP_MEMORY_SCOPE_AGENT);
      } while ((uint32)(v >> 32) != gs);
      hpeer[t] = (uint32)v;
    }
    bar_lds();                          // BAR-1: peer half deposited (LDS-only drain)
    // peer h-slice + peer-half partial dots
    uint32 hrp[8];
    *(uint4*)&hrp[0] = *(const uint4*)&hpeer[8 * kap];
    *(uint4*)&hrp[4] = *(const uint4*)&hpeer[8 * kap + 4];
#pragma unroll
    for (int j = 0; j < 8; ++j) {
      float a = acc[j];
#pragma unroll
      for (int m = 0; m < 8; ++m) a = fdot2(wr[j * 16 + 8 + m], hrp[m], a);
      acc[j] = a;
    }
    float s = bfly8(acc, kap);          // lane owns row R (rho = kap)
    float pre = s + xcur;
    xcur = xnext;
    // one exp per lane; q==2 uses tanh via 2*sigm(2x)-1 (exact doubling)
    float z = (q == 2) ? (2.f * pre) : pre;
    float sg = 1.f / (1.f + __expf(-z));
    float a_own = (q == 2) ? (2.f * sg - 1.f) : sg;
    // gather 4 gates of unit u (lanes l, l^16, l^32, l^48) - verified table
    float a1 = __shfl_xor(a_own, 16, 64);
    float a2 = __shfl_xor(a_own, 32, 64);
    float a3 = __shfl_xor(a1, 32, 64);
    float gi = (q == 0) ? a_own : ((q == 1) ? a1 : ((q == 2) ? a2 : a3));
    float gf = (q == 1) ? a_own : ((q == 0) ? a1 : ((q == 3) ? a2 : a3));
    float gg = (q == 2) ? a_own : ((q == 3) ? a1 : ((q == 0) ? a2 : a3));
    float go = (q == 3) ? a_own : ((q == 2) ? a1 : ((q == 1) ? a2 : a3));
    c = gf * c + gi * gg;               // redundant x4, deterministic
    float h = go * tanh_fast(c);
    _Float16 hf16 = (_Float16)h;
    uint32 hz = (uint32)__builtin_bit_cast(unsigned short, hf16);
    uint32 hn = (uint32)__shfl_xor((int)hz, 1, 64);   // partner unit u^1
    if (q == 0) {
      ((unsigned short*)&hown[(tt + 1) & 1][0])[u] = (unsigned short)hz;
      ostage[tt & 15][u] = h;
      if (ch == NCH - 1 && tt == CH - 1) {
        float* os = out + (size_t)LSTM_N * LSTM_T * LSTM_H + n * 512;
        os[128 * p + u] = h;
        os[256 + 128 * p + u] = c;
      }
    }
    bar_lds();                          // BAR-2: hown/ostage visible (LDS-only drain)
    // post AFTER the barrier: store latency never gates a drain; peer
    // consumes it >=1 own-dots phase later (lockstep) -> arrives in time.
    if (q == 0 && tt < CH - 1 && (l & 1) == 0) {
      uint64 msg = (uint64)(hz | (hn << 16)) | ((uint64)(gs + 1) << 32);
      __hip_atomic_store(&hx_own[(size_t)((tt + 1) & 1) * 64 + (u >> 1)], msg,
                         __ATOMIC_RELAXED, __HIP_MEMORY_SCOPE_AGENT);
    }
    if ((tt & 15) == 15) {              // flush 16 staged steps, coalesced
      int sl = t >> 5, q4 = t & 31;
      float4 v = *(const float4*)&ostage[sl][4 * q4];
      *(float4*)&outb[(size_t)(tt - 15 + sl) * LSTM_H + 128 * p + 4 * q4] = v;
    }
  }
  // persist carried state (CH even -> final h landed in hown[0])
  if (q == 0) cst[n * 256 + 128 * p + u] = c;
  if (t < 64) hst[n * 128 + 64 * p + t] = hown[0][t];
}

extern "C" void kernel_launch(void* const* d_in, const int* in_sizes, int n_in,
                              void* d_out, int out_size, void* d_ws, size_t ws_size,
                              hipStream_t stream) {
  const float* x   = (const float*)d_in[0];
  const float* st  = (const float*)d_in[1];
  const float* wih = (const float*)d_in[2];
  const float* whh = (const float*)d_in[3];
  const float* bih = (const float*)d_in[4];
  const float* bhh = (const float*)d_in[5];
  float* out = (float*)d_out;
  char* ws = (char*)d_ws;

  float* xg = (float*)(ws + OFF_XG);
  unsigned short* wihb = (unsigned short*)(ws + OFF_WIHB);
  float* bias = (float*)(ws + OFF_BIAS);
  uint32* wpk = (uint32*)(ws + OFF_WPK);
  float* cst = (float*)(ws + OFF_CST);
  uint32* hst = (uint32*)(ws + OFF_HST);
  uint64* hx = (uint64*)(ws + OFF_HX);

  cvt_bf16_k<<<(NG * LSTM_D / 4 + 255) / 256, 256, 0, stream>>>(wih, wihb, NG * LSTM_D);
  bias_sum_k<<<4, 256, 0, stream>>>(bih, bhh, bias);
  wpack_k<<<512, 256, 0, stream>>>(whh, wpk);
  state_init_k<<<32, 256, 0, stream>>>(st, cst, hst, hx);

  for (int ch = 0; ch < NCH; ++ch) {
    gemm_xg<<<dim3(NG / 128, MCH / 128), 256, 0, stream>>>(x, wihb, bias, xg, ch);
    lstm_scan<<<64, 512, 0, stream>>>(xg, (const uint4*)wpk, cst, hst, hx, out, ch);
  }
}

// Round 17
// 3161.716 us; speedup vs baseline: 2.1418x; 1.0899x over previous
//
#include <hip/hip_runtime.h>

typedef _Float16 half2_t __attribute__((ext_vector_type(2)));
typedef __bf16   bf16x8  __attribute__((ext_vector_type(8)));
typedef float    f32x4   __attribute__((ext_vector_type(4)));
typedef unsigned short u16x8 __attribute__((ext_vector_type(8)));
typedef unsigned int  uint32;
typedef unsigned long long uint64;

#define LSTM_N 32
#define LSTM_T 2048
#define LSTM_D 256
#define LSTM_H 256
#define NG 1024
#define CH 256                    // time-chunk length
#define NCH (LSTM_T / CH)         // 8 chunks
#define MCH (LSTM_N * CH)         // 8192 rows per chunk GEMM

// ---- workspace layout (bytes) ---- (~34.7 MB, R9 layout)
#define OFF_XG   ((size_t)0)
#define SZ_XG    ((size_t)MCH * NG * 4)             // 33,554,432 xg chunk f32
#define OFF_WIHB (OFF_XG + SZ_XG)
#define SZ_WIHB  ((size_t)NG * LSTM_D * 2)          // w_ih bf16
#define OFF_BIAS (OFF_WIHB + SZ_WIHB)
#define SZ_BIAS  ((size_t)4096)
#define OFF_WPK  (OFF_BIAS + SZ_BIAS)
#define SZ_WPK   ((size_t)2 * 512 * 128 * 4)        // 524,288 w_hh f16 pairs (R9 layout)
#define OFF_CST  (OFF_WPK + SZ_WPK)
#define SZ_CST   ((size_t)LSTM_N * 256 * 4)         // c state f32
#define OFF_HST  (OFF_CST + SZ_CST)
#define SZ_HST   ((size_t)LSTM_N * 128 * 4)         // h state f16-pairs (u32)
#define OFF_HX   (OFF_HST + SZ_HST)
#define SZ_HX    ((size_t)LSTM_N * 2 * 2 * 64 * 8)  // 65,536 tagged-u64 exchange slots

#if defined(__has_builtin)
#if __has_builtin(__builtin_amdgcn_fdot2)
#define HAVE_FDOT2 1
#endif
#endif

// PROVEN datapath (R2/R3/R6/R8/R9/R12, absmax 0.0078). Inline-asm v_dot2 is
// numerically WRONG on gfx950 (R5/R7 failed identically) - permanently banned.
__device__ __forceinline__ float fdot2(uint32 w, uint32 h, float acc) {
#ifdef HAVE_FDOT2
  return __builtin_amdgcn_fdot2(__builtin_bit_cast(half2_t, w),
                                __builtin_bit_cast(half2_t, h), acc, false);
#else
  half2_t wv = __builtin_bit_cast(half2_t, w);
  half2_t hv = __builtin_bit_cast(half2_t, h);
  float r = fmaf((float)wv.x, (float)hv.x, acc);
  return fmaf((float)wv.y, (float)hv.y, r);
#endif
}

__device__ __forceinline__ float tanh_fast(float x) { return 2.f / (1.f + __expf(-2.f * x)) - 1.f; }

__device__ __forceinline__ unsigned short f2bf(float f) {
  uint32 u = __builtin_bit_cast(uint32, f);
  uint32 r = (u + 0x7FFFu + ((u >> 16) & 1u)) >> 16;
  return (unsigned short)r;
}

// LDS-only barrier (T4): __syncthreads drains vmcnt(0) too, serializing the
// in-flight xg prefetch (~300-500cy) and post store (~200-300cy) into every
// step. All cross-wave hazards here are LDS -> lgkmcnt(0) suffices. The
// poller's hpeer ds_write issues only after its tag compare (data-dep vmcnt
// wait), so lgkm drain is sound at BAR-1. sched_barrier(0) per rule #18.
__device__ __forceinline__ void bar_lds() {
  asm volatile("s_waitcnt lgkmcnt(0)" ::: "memory");
  __builtin_amdgcn_s_barrier();
  __builtin_amdgcn_sched_barrier(0);
}

// reduce-scatter over 8 kappa-lanes (masks 4/2/1 -> in-wave). R9-proven.
__device__ __forceinline__ float bfly8(const float a[8], int kap) {
  float k0[4], g0[4];
  const bool b4 = (kap & 4) != 0;
#pragma unroll
  for (int v = 0; v < 4; ++v) {
    k0[v] = b4 ? a[v + 4] : a[v];
    g0[v] = b4 ? a[v] : a[v + 4];
  }
#pragma unroll
  for (int v = 0; v < 4; ++v) k0[v] += __shfl_xor(g0[v], 4, 64);
  float k1[2], g1[2];
  const bool b2 = (kap & 2) != 0;
#pragma unroll
  for (int v = 0; v < 2; ++v) {
    k1[v] = b2 ? k0[v + 2] : k0[v];
    g1[v] = b2 ? k0[v] : k0[v + 2];
  }
#pragma unroll
  for (int v = 0; v < 2; ++v) k1[v] += __shfl_xor(g1[v], 2, 64);
  const bool b1 = (kap & 1) != 0;
  float k2 = b1 ? k1[1] : k1[0];
  float g2 = b1 ? k1[0] : k1[1];
  return k2 + __shfl_xor(g2, 1, 64);
}

// ---------------- kernels (cvt/bias/wpack/state_init/gemm = R9 verbatim) ----------------

__global__ void cvt_bf16_k(const float* __restrict__ src, unsigned short* __restrict__ dst, int n) {
  int i = blockIdx.x * blockDim.x + threadIdx.x;
  if (4 * i + 3 < n) {
    float4 v = ((const float4*)src)[i];
    ushort4 o;
    o.x = f2bf(v.x); o.y = f2bf(v.y); o.z = f2bf(v.z); o.w = f2bf(v.w);
    ((ushort4*)dst)[i] = o;
  }
}

__global__ void bias_sum_k(const float* __restrict__ bih, const float* __restrict__ bhh,
                           float* __restrict__ bias) {
  int g = blockIdx.x * blockDim.x + threadIdx.x;
  if (g < NG) bias[g] = bih[g] + bhh[g];
}

// Pack w_hh f32[1024][256] -> f16-pair images for scan WG-half p, thread t.
// Thread t: w=t>>6, l=t&63, q=l>>4, b3=(l>>3)&1, kap=l&7.
// wr[j*16+m]: row = q*256+128p+16w+8b3+j (j=0..7);
//             k = m<8 ? 128p+16kap+2m : 128(1-p)+16kap+2(m-8).   [R9 verbatim]
__global__ void wpack_k(const float* __restrict__ whh, uint32* __restrict__ wpk) {
  int e = blockIdx.x * blockDim.x + threadIdx.x;  // < 131072
  int p = e >> 16;
  int i128 = (e >> 9) & 127;
  int t = e & 511;
  int j = i128 >> 4, m = i128 & 15;
  int w = t >> 6, l = t & 63;
  int q = l >> 4, b3 = (l >> 3) & 1, kap = l & 7;
  int row = q * 256 + 128 * p + 16 * w + 8 * b3 + j;
  int k = (m < 8) ? (128 * p + 16 * kap + 2 * m)
                  : (128 * (1 - p) + 16 * kap + 2 * (m - 8));
  half2_t h;
  h.x = (_Float16)whh[row * 256 + k];
  h.y = (_Float16)whh[row * 256 + k + 1];
  wpk[((i128 >> 2) * 1024 + p * 512 + t) * 4 + (i128 & 3)] = __builtin_bit_cast(uint32, h);
}

// init carried state + zero exchange tags (every launch -> replay-safe) [R9 verbatim]
__global__ void state_init_k(const float* __restrict__ state, float* __restrict__ cst,
                             uint32* __restrict__ hst, uint64* __restrict__ hx) {
  int i = blockIdx.x * blockDim.x + threadIdx.x;  // < 8192
  int n = i >> 8, j = i & 255;
  cst[i] = state[n * 512 + 256 + j];
  if ((j & 1) == 0) {
    half2_t h2;
    h2.x = (_Float16)state[n * 512 + j];
    h2.y = (_Float16)state[n * 512 + j + 1];
    hst[(n << 7) + (j >> 1)] = __builtin_bit_cast(uint32, h2);
  }
  hx[i] = 0ull;
}

// xg[8192][1024] = x(chunk rows, cvt bf16 inline) @ w_ih_bf16^T + bias  [R2/R3 verbatim]
__global__ __launch_bounds__(256) void gemm_xg(const float* __restrict__ x,
                                               const unsigned short* __restrict__ wb,
                                               const float* __restrict__ bias,
                                               float* __restrict__ xg, int ch) {
  __shared__ unsigned short As[128 * 40];  // 80B rows (stride = 5*16B, odd*16)
  __shared__ unsigned short Bs[128 * 40];
  const int tid = threadIdx.x;
  const int m0 = blockIdx.y * 128;
  const int g0 = blockIdx.x * 128;
  const int w = tid >> 6;
  const int lane = tid & 63;
  const int wm = (w >> 1) * 64, wn = (w & 1) * 64;
  const int row_l = tid >> 2;  // 0..63
  const int q = tid & 3;
  const int lr = lane & 15, kg = lane >> 4;

  size_t grow[2];
#pragma unroll
  for (int r = 0; r < 2; ++r) {
    int gm = m0 + row_l + 64 * r;
    grow[r] = (size_t)(gm >> 8) * LSTM_T + (size_t)ch * CH + (gm & 255);
  }

  f32x4 acc[4][4];
#pragma unroll
  for (int i = 0; i < 4; ++i)
#pragma unroll
    for (int j = 0; j < 4; ++j) acc[i][j] = (f32x4){0.f, 0.f, 0.f, 0.f};

  for (int kt = 0; kt < 8; ++kt) {
#pragma unroll
    for (int r = 0; r < 2; ++r) {
      int row = row_l + 64 * r;
      const float* ap = x + grow[r] * 256 + kt * 32 + q * 8;
      float4 v0 = *(const float4*)ap;
      float4 v1 = *(const float4*)(ap + 4);
      u16x8 o;
      o[0] = f2bf(v0.x); o[1] = f2bf(v0.y); o[2] = f2bf(v0.z); o[3] = f2bf(v0.w);
      o[4] = f2bf(v1.x); o[5] = f2bf(v1.y); o[6] = f2bf(v1.z); o[7] = f2bf(v1.w);
      *(uint4*)((char*)As + row * 80 + q * 16) = __builtin_bit_cast(uint4, o);
      uint4 bv = *(const uint4*)(wb + (size_t)(g0 + row) * 256 + kt * 32 + q * 8);
      *(uint4*)((char*)Bs + row * 80 + q * 16) = bv;
    }
    __syncthreads();
    bf16x8 af[4], bfr[4];
#pragma unroll
    for (int i = 0; i < 4; ++i)
      af[i] = __builtin_bit_cast(bf16x8, *(const uint4*)((char*)As + (wm + 16 * i + lr) * 80 + kg * 16));
#pragma unroll
    for (int j = 0; j < 4; ++j)
      bfr[j] = __builtin_bit_cast(bf16x8, *(const uint4*)((char*)Bs + (wn + 16 * j + lr) * 80 + kg * 16));
#pragma unroll
    for (int i = 0; i < 4; ++i)
#pragma unroll
      for (int j = 0; j < 4; ++j)
        acc[i][j] = __builtin_amdgcn_mfma_f32_16x16x32_bf16(af[i], bfr[j], acc[i][j], 0, 0, 0);
    __syncthreads();
  }
#pragma unroll
  for (int j = 0; j < 4; ++j) {
    int gc = g0 + wn + 16 * j + lr;
    float bj = bias[gc];
#pragma unroll
    for (int i = 0; i < 4; ++i) {
#pragma unroll
      for (int r = 0; r < 4; ++r) {
        int m = m0 + wm + 16 * i + kg * 4 + r;
        xg[(size_t)m * NG + gc] = acc[i][j][r] + bj;
      }
    }
  }
}

// Recurrent scan: R9 EXACT (datapath, protocol, post position) with ONE change:
// in-loop barriers drain lgkmcnt only (bar_lds) - the xg prefetch and the
// exchange post stay in flight across barriers instead of serializing into
// them. Thread t: kap=t&7, q=(t&63)>>4, u=16*(t>>6)+(t&15), R=q*256+128p+u.
__global__ __launch_bounds__(512, 1) void lstm_scan(const float* __restrict__ xg,
                                                    const uint4* __restrict__ wpk4,
                                                    float* __restrict__ cst,
                                                    uint32* __restrict__ hst,
                                                    uint64* __restrict__ hx,
                                                    float* __restrict__ out, int ch) {
  __shared__ uint32 hown[2][64];      // own-half h f16-pairs, parity per step
  __shared__ uint32 hpeer[64];        // peer-half deposit (single buffer, R9-proven)
  __shared__ float ostage[16][128];   // h staging, flushed every 16 steps

  const int b = blockIdx.x;
  const int n = b & 31;
  const int p = b >> 5;
  const int t = threadIdx.x;
  const int w = t >> 6, l = t & 63;
  const int q = l >> 4, kap = l & 7;
  const int u = 16 * w + (l & 15);      // unit within half
  const int R = q * 256 + 128 * p + u;  // finalized gate row

  // weights -> 128 regs (AGPR split accepted; builtin fdot2 pays the copy)
  uint32 wr[128];
#pragma unroll
  for (int ig = 0; ig < 32; ++ig) {
    uint4 v = wpk4[ig * 1024 + p * 512 + t];
    wr[4 * ig + 0] = v.x; wr[4 * ig + 1] = v.y; wr[4 * ig + 2] = v.z; wr[4 * ig + 3] = v.w;
  }
  float c = cst[n * 256 + 128 * p + u];   // 4-way redundant (broadcast load)
  if (t < 64) {
    hown[0][t] = hst[n * 128 + 64 * p + t];
    hpeer[t]   = hst[n * 128 + 64 * (1 - p) + t];  // step-0 peer half
  }
  __syncthreads();

  const float* xgn = xg + (size_t)n * CH * NG;
  float* outb = out + ((size_t)n * LSTM_T + (size_t)ch * CH) * LSTM_H;
  uint64* hx_own  = hx + (size_t)(n * 2 + p) * 128;
  uint64* hx_peer = hx + (size_t)(n * 2 + (1 - p)) * 128;
  const int gsbase = ch * CH;

  float xcur = xgn[R];

  for (int tt = 0; tt < CH; ++tt) {
    const uint32 gs = (uint32)(gsbase + tt);
    // xg prefetch for next step (stays in flight across bar_lds)
    float xnext = (tt < CH - 1) ? xgn[(size_t)(tt + 1) * NG + R] : 0.f;
    // own h-slice (broadcast LDS reads, parity buffer)
    uint32 hro[8];
    *(uint4*)&hro[0] = *(const uint4*)&hown[tt & 1][8 * kap];
    *(uint4*)&hro[4] = *(const uint4*)&hown[tt & 1][8 * kap + 4];
    // own-half partial dots FIRST (8 rows x 8 pairs) - overlaps peer posting
    float acc[8];
#pragma unroll
    for (int j = 0; j < 8; ++j) {
      float a = 0.f;
#pragma unroll
      for (int m = 0; m < 8; ++m) a = fdot2(wr[j * 16 + m], hro[m], a);
      acc[j] = a;
    }
    // designated pollers: 1 tagged slot each (R3/R9-proven protocol, relaxed)
    if (tt > 0 && t < 64) {
      uint64 v;
      do {
        v = __hip_atomic_load(&hx_peer[(size_t)(tt & 1) * 64 + t],
                              __ATOMIC_RELAXED, __HIP_MEMORY_SCOPE_AGENT);
      } while ((uint32)(v >> 32) != gs);
      hpeer[t] = (uint32)v;
    }
    bar_lds();                          // BAR-1: peer half deposited (lgkm-only)
    // peer h-slice + peer-half partial dots
    uint32 hrp[8];
    *(uint4*)&hrp[0] = *(const uint4*)&hpeer[8 * kap];
    *(uint4*)&hrp[4] = *(const uint4*)&hpeer[8 * kap + 4];
#pragma unroll
    for (int j = 0; j < 8; ++j) {
      float a = acc[j];
#pragma unroll
      for (int m = 0; m < 8; ++m) a = fdot2(wr[j * 16 + 8 + m], hrp[m], a);
      acc[j] = a;
    }
    float s = bfly8(acc, kap);          // lane owns row R (rho = kap)
    float pre = s + xcur;
    xcur = xnext;
    // one exp per lane; q==2 uses tanh via 2*sigm(2x)-1 (exact doubling)
    float z = (q == 2) ? (2.f * pre) : pre;
    float sg = 1.f / (1.f + __expf(-z));
    float a_own = (q == 2) ? (2.f * sg - 1.f) : sg;
    // gather 4 gates of unit u (lanes l, l^16, l^32, l^48) - verified table
    float a1 = __shfl_xor(a_own, 16, 64);
    float a2 = __shfl_xor(a_own, 32, 64);
    float a3 = __shfl_xor(a1, 32, 64);
    float gi = (q == 0) ? a_own : ((q == 1) ? a1 : ((q == 2) ? a2 : a3));
    float gf = (q == 1) ? a_own : ((q == 0) ? a1 : ((q == 3) ? a2 : a3));
    float gg = (q == 2) ? a_own : ((q == 3) ? a1 : ((q == 0) ? a2 : a3));
    float go = (q == 3) ? a_own : ((q == 2) ? a1 : ((q == 1) ? a2 : a3));
    c = gf * c + gi * gg;               // redundant x4, deterministic
    float h = go * tanh_fast(c);
    _Float16 hf16 = (_Float16)h;
    uint32 hz = (uint32)__builtin_bit_cast(unsigned short, hf16);
    uint32 hn = (uint32)__shfl_xor((int)hz, 1, 64);   // partner unit u^1
    if (q == 0) {
      ((unsigned short*)&hown[(tt + 1) & 1][0])[u] = (unsigned short)hz;
      ostage[tt & 15][u] = h;
      if (tt < CH - 1 && (l & 1) == 0) {  // post pair (u,u+1), tag = gs+1 (R9 position)
        uint64 msg = (uint64)(hz | (hn << 16)) | ((uint64)(gs + 1) << 32);
        __hip_atomic_store(&hx_own[(size_t)((tt + 1) & 1) * 64 + (u >> 1)], msg,
                           __ATOMIC_RELAXED, __HIP_MEMORY_SCOPE_AGENT);
      }
      if (ch == NCH - 1 && tt == CH - 1) {
        float* os = out + (size_t)LSTM_N * LSTM_T * LSTM_H + n * 512;
        os[128 * p + u] = h;
        os[256 + 128 * p + u] = c;
      }
    }
    bar_lds();                          // BAR-2: hown/ostage visible (lgkm-only)
    if ((tt & 15) == 15) {              // flush 16 staged steps, coalesced
      int sl = t >> 5, q4 = t & 31;
      float4 v = *(const float4*)&ostage[sl][4 * q4];
      *(float4*)&outb[(size_t)(tt - 15 + sl) * LSTM_H + 128 * p + 4 * q4] = v;
    }
  }
  // persist carried state (CH even -> final h landed in hown[0])
  if (q == 0) cst[n * 256 + 128 * p + u] = c;
  if (t < 64) hst[n * 128 + 64 * p + t] = hown[0][t];
}

extern "C" void kernel_launch(void* const* d_in, const int* in_sizes, int n_in,
                              void* d_out, int out_size, void* d_ws, size_t ws_size,
                              hipStream_t stream) {
  const float* x   = (const float*)d_in[0];
  const float* st  = (const float*)d_in[1];
  const float* wih = (const float*)d_in[2];
  const float* whh = (const float*)d_in[3];
  const float* bih = (const float*)d_in[4];
  const float* bhh = (const float*)d_in[5];
  float* out = (float*)d_out;
  char* ws = (char*)d_ws;

  float* xg = (float*)(ws + OFF_XG);
  unsigned short* wihb = (unsigned short*)(ws + OFF_WIHB);
  float* bias = (float*)(ws + OFF_BIAS);
  uint32* wpk = (uint32*)(ws + OFF_WPK);
  float* cst = (float*)(ws + OFF_CST);
  uint32* hst = (uint32*)(ws + OFF_HST);
  uint64* hx = (uint64*)(ws + OFF_HX);

  cvt_bf16_k<<<(NG * LSTM_D / 4 + 255) / 256, 256, 0, stream>>>(wih, wihb, NG * LSTM_D);
  bias_sum_k<<<4, 256, 0, stream>>>(bih, bhh, bias);
  wpack_k<<<512, 256, 0, stream>>>(whh, wpk);
  state_init_k<<<32, 256, 0, stream>>>(st, cst, hst, hx);

  for (int ch = 0; ch < NCH; ++ch) {
    gemm_xg<<<dim3(NG / 128, MCH / 128), 256, 0, stream>>>(x, wihb, bias, xg, ch);
    lstm_scan<<<64, 512, 0, stream>>>(xg, (const uint4*)wpk, cst, hst, hx, out, ch);
  }
}